// Round 1
// baseline (16.274 us; speedup 1.0000x reference)
//
#include <hip/hip_runtime.h>

// CPLSTM_1245540516200
//
// Observation (bit-exact, input-independent):
//   h0 = c0 = 0 and gates = (h @ a) * (x_t @ b)  -- elementwise product.
//   h=0  =>  h@a = 0  =>  gates = 0  =>  g = 0
//        =>  f = i = o = sigmoid(0) = 0.5, g_t = tanh(0) = 0
//        =>  c' = 0.5*0 + 0.5*0 = 0,  h' = 0.5*tanh(0) = 0.
//   By induction h_t = c_t = 0 for all t, for ANY values of inp/E/a/b/ct.
//   Therefore the reference output (hidden_seq, h_T, c_T) is identically 0.0f.
//
// The optimal kernel is a pure zero-fill of d_out: HBM-write-bound,
// 67,371,008 bytes. Vectorized float4 grid-stride stores.

__global__ __launch_bounds__(256) void CPLSTM_zero_fill(float4* __restrict__ out4,
                                                        long n4,
                                                        float* __restrict__ out_tail,
                                                        long tail_start,
                                                        long n_total) {
    long i = (long)blockIdx.x * blockDim.x + threadIdx.x;
    const long stride = (long)gridDim.x * blockDim.x;
    const float4 z = make_float4(0.f, 0.f, 0.f, 0.f);
    for (long k = i; k < n4; k += stride) {
        out4[k] = z;
    }
    // Defensive scalar tail (out_size is a multiple of 4 here, so this is a no-op,
    // but keep it so the kernel is correct for any out_size).
    long t = tail_start + i;
    if (t < n_total) {
        out_tail[t] = 0.f;
    }
}

extern "C" void kernel_launch(void* const* d_in, const int* in_sizes, int n_in,
                              void* d_out, int out_size, void* d_ws, size_t ws_size,
                              hipStream_t stream) {
    (void)d_in; (void)in_sizes; (void)n_in; (void)d_ws; (void)ws_size;

    float* out = (float*)d_out;
    const long n = (long)out_size;       // B*T*H + B*H + B*H = 16,842,752 f32
    const long n4 = n >> 2;              // float4 count
    const long tail_start = n4 << 2;

    // 4096 blocks x 256 threads: ~1M threads, ~4 float4 stores each (grid-stride).
    CPLSTM_zero_fill<<<4096, 256, 0, stream>>>((float4*)out, n4, out, tail_start, n);
}

// Round 3
// 15.545 us; speedup vs baseline: 1.0469x; 1.0469x over previous
//
#include <hip/hip_runtime.h>

// CPLSTM_1245540516200
//
// Observation (bit-exact, input-independent):
//   h0 = c0 = 0 and gates = (h @ a) * (x_t @ b)  -- elementwise product.
//   h=0  =>  h@a = 0  =>  gates = 0  =>  g = 0
//        =>  f = i = o = sigmoid(0) = 0.5, g_t = tanh(0) = 0
//        =>  c' = 0.5*0 + 0.5*0 = 0,  h' = 0.5*tanh(0) = 0.
//   By induction h_t = c_t = 0 for all t, for ANY values of inp/E/a/b/ct.
//   The reference output (hidden_seq, h_T, c_T) is identically 0.0f.
//
// Optimal kernel = zero-fill of d_out (67,371,008 B), HBM-write-bound.
// R2 fix: __builtin_nontemporal_store needs a native clang vector type,
// not HIP's float4 class -> use ext_vector_type(4).

typedef float floatx4 __attribute__((ext_vector_type(4)));

__global__ __launch_bounds__(256) void CPLSTM_zero_fill(floatx4* __restrict__ out4,
                                                        long n4,
                                                        float* __restrict__ out_tail,
                                                        long tail_start,
                                                        long n_total) {
    const long i = (long)blockIdx.x * blockDim.x + threadIdx.x;
    if (i < n4) {
        const floatx4 z = {0.f, 0.f, 0.f, 0.f};
        __builtin_nontemporal_store(z, &out4[i]);
    }
    // Defensive scalar tail (no-op here: out_size % 4 == 0).
    const long t = tail_start + i;
    if (t < n_total) {
        out_tail[t] = 0.f;
    }
}

extern "C" void kernel_launch(void* const* d_in, const int* in_sizes, int n_in,
                              void* d_out, int out_size, void* d_ws, size_t ws_size,
                              hipStream_t stream) {
    (void)d_in; (void)in_sizes; (void)n_in; (void)d_ws; (void)ws_size;

    float* out = (float*)d_out;
    const long n = (long)out_size;       // 16,842,752 f32 = 67,371,008 bytes
    const long n4 = n >> 2;              // 4,210,688 float4
    const long tail_start = n4 << 2;

    const int block = 256;
    const long grid = (n4 + block - 1) / block;   // 16448 exactly
    CPLSTM_zero_fill<<<(int)grid, block, 0, stream>>>((floatx4*)out, n4, out, tail_start, n);
}